// Round 2
// baseline (1707.772 us; speedup 1.0000x reference)
//
#include <hip/hip_runtime.h>

#define Bv 1024
#define Ev 256
#define Lv 8
#define Rv 10000
#define NP1 10001
#define PSTR 10016   // padded K stride for softmax@emb_w (multiple of 32)

typedef __attribute__((ext_vector_type(8))) short bf16x8;
typedef __attribute__((ext_vector_type(4))) float f32x4;

__device__ __forceinline__ float b2f(unsigned short u) {
    union { unsigned int i; float f; } v; v.i = ((unsigned int)u) << 16; return v.f;
}
__device__ __forceinline__ unsigned short f2b(float f) {
    union { float f; unsigned int i; } v; v.f = f;
    unsigned int r = v.i + 0x7fffu + ((v.i >> 16) & 1u);
    return (unsigned short)(r >> 16);
}

// C = A1·W1^T (+ A2·W2^T) + bias1 (+ bias2); A,W bf16; bias f32; f32 accum.
// A: (1024 x K) row-major stride lda; W: (Ncols x K) row-major stride ldw.
// mode 0: write f32 C     mode 1: write bf16 relu(C)     mode 2: atomicAdd f32
__global__ __launch_bounds__(256) void gemm_bt(
    const unsigned short* __restrict__ A1, int lda1,
    const unsigned short* __restrict__ W1, int ldw1,
    const unsigned short* __restrict__ A2, int lda2,
    const unsigned short* __restrict__ W2, int ldw2,
    const float* __restrict__ bias1,
    const float* __restrict__ bias2,
    int Ktot, int kchunk, int Ncols, int mode,
    float* __restrict__ outF, unsigned short* __restrict__ outB, int ldc)
{
    int tid  = threadIdx.x;
    int wave = tid >> 6;
    int lane = tid & 63;
    int quad = lane >> 4;
    int l16  = lane & 15;
    int mRow  = blockIdx.x * 64 + wave * 16 + l16;   // A row this lane loads
    int nBase = blockIdx.y * 64;
    int k0 = blockIdx.z * kchunk;
    int k1 = k0 + kchunk; if (k1 > Ktot) k1 = Ktot;

    f32x4 acc[4];
#pragma unroll
    for (int t = 0; t < 4; ++t) acc[t] = (f32x4){0.f, 0.f, 0.f, 0.f};

    int nIdx[4];
#pragma unroll
    for (int t = 0; t < 4; ++t) {
        int n = nBase + t * 16 + l16;
        nIdx[t] = (n < Ncols) ? n : (Ncols - 1);
    }

    for (int k = k0; k < k1; k += 32) {
        bf16x8 a = *(const bf16x8*)(A1 + (size_t)mRow * lda1 + k + quad * 8);
#pragma unroll
        for (int t = 0; t < 4; ++t) {
            bf16x8 b = *(const bf16x8*)(W1 + (size_t)nIdx[t] * ldw1 + k + quad * 8);
            acc[t] = __builtin_amdgcn_mfma_f32_16x16x32_bf16(a, b, acc[t], 0, 0, 0);
        }
    }
    if (A2) {
        for (int k = k0; k < k1; k += 32) {
            bf16x8 a = *(const bf16x8*)(A2 + (size_t)mRow * lda2 + k + quad * 8);
#pragma unroll
            for (int t = 0; t < 4; ++t) {
                bf16x8 b = *(const bf16x8*)(W2 + (size_t)nIdx[t] * ldw2 + k + quad * 8);
                acc[t] = __builtin_amdgcn_mfma_f32_16x16x32_bf16(a, b, acc[t], 0, 0, 0);
            }
        }
    }

    // D mapping: col = lane&15, row = (lane>>4)*4 + reg  [guide §3, m89-verified]
    int mOutBase = blockIdx.x * 64 + wave * 16 + quad * 4;
#pragma unroll
    for (int t = 0; t < 4; ++t) {
        int n = nBase + t * 16 + l16;
        if (n >= Ncols) continue;
        float bsum = 0.f;
        if (bias1) bsum += bias1[n];
        if (bias2) bsum += bias2[n];
#pragma unroll
        for (int r = 0; r < 4; ++r) {
            int m = mOutBase + r;
            float v = acc[t][r] + bsum;
            if (mode == 0) {
                outF[(size_t)m * ldc + n] = v;
            } else if (mode == 1) {
                outB[(size_t)m * ldc + n] = f2b(v > 0.f ? v : 0.f);
            } else {
                atomicAdd(&outF[(size_t)m * ldc + n], v);
            }
        }
    }
}

// generic f32 -> bf16 copy
__global__ void conv_f2b(const float* __restrict__ src,
                         unsigned short* __restrict__ dst, int n)
{
    for (int i = blockIdx.x * 256 + threadIdx.x; i < n; i += gridDim.x * 256)
        dst[i] = f2b(src[i]);
}

__global__ void embed_k(const int* __restrict__ bodys,
                        const float* __restrict__ emb_w,
                        unsigned short* __restrict__ x)
{
    int blk = blockIdx.x;  // b*L + l
    x[(size_t)blk * Ev + threadIdx.x] =
        f2b(emb_w[(size_t)bodys[blk] * Ev + threadIdx.x]);
}

__global__ void transpose_emb(const float* __restrict__ emb_w,
                              unsigned short* __restrict__ embT)
{
    int e = blockIdx.y;
    int k = blockIdx.x * 256 + threadIdx.x;
    if (k < PSTR)
        embT[(size_t)e * PSTR + k] =
            (k < Rv) ? f2b(emb_w[(size_t)k * Ev + e]) : (unsigned short)0;
}

__global__ void lstm_gates(const float* __restrict__ g, float* __restrict__ c,
                           unsigned short* __restrict__ hout, int t)
{
    int b = blockIdx.x, e = threadIdx.x;
    const float* gr = g + (size_t)b * 1024;
    float gi = gr[e], gf = gr[256 + e], gc = gr[512 + e], go = gr[768 + e];
    float cp = (t == 0) ? 0.f : c[b * Ev + e];
    float si = 1.f / (1.f + expf(-gi));
    float sf = 1.f / (1.f + expf(-gf));
    float so = 1.f / (1.f + expf(-go));
    float cn = sf * cp + si * tanhf(gc);
    float hn = so * tanhf(cn);
    c[b * Ev + e] = cn;
    hout[b * Ev + e] = f2b(hn);
}

__global__ __launch_bounds__(256) void softmax_k(const float* __restrict__ prob,
                                                 unsigned short* __restrict__ sfA,
                                                 float* __restrict__ sfLast)
{
    int b = blockIdx.x, tid = threadIdx.x;
    int wave = tid >> 6, lane = tid & 63;
    __shared__ float redm[4], reds[4];
    const float* pr = prob + (size_t)b * PSTR;
    float m = -1e30f;
    for (int k = tid; k < NP1; k += 256) m = fmaxf(m, pr[k]);
    for (int off = 32; off; off >>= 1) m = fmaxf(m, __shfl_down(m, off));
    if (lane == 0) redm[wave] = m;
    __syncthreads();
    m = fmaxf(fmaxf(redm[0], redm[1]), fmaxf(redm[2], redm[3]));
    float s = 0.f;
    for (int k = tid; k < NP1; k += 256) s += expf(pr[k] - m);
    for (int off = 32; off; off >>= 1) s += __shfl_down(s, off);
    if (lane == 0) reds[wave] = s;
    __syncthreads();
    s = reds[0] + reds[1] + reds[2] + reds[3];
    float inv = 1.f / s;
    for (int k = tid; k < PSTR; k += 256) {
        size_t idx = (size_t)b * PSTR + k;
        if (k < Rv) {
            sfA[idx] = f2b(expf(pr[k] - m) * inv);
        } else {
            sfA[idx] = 0;
            if (k == Rv) sfLast[b] = expf(pr[k] - m) * inv;
        }
    }
}

// i == 0: emb_concat = [x[:,0,:], x[:,1,:]]  (bf16 operand + f32 copy)
__global__ void concat0(const int* __restrict__ bodys,
                        const float* __restrict__ emb_w,
                        unsigned short* __restrict__ embc,
                        float* __restrict__ embcF)
{
    int b = blockIdx.x, e = threadIdx.x;
    float v0 = emb_w[(size_t)bodys[b * Lv + 0] * Ev + e];
    float v1 = emb_w[(size_t)bodys[b * Lv + 1] * Ev + e];
    embcF[(size_t)b * 512 + e]       = v0;
    embcF[(size_t)b * 512 + 256 + e] = v1;
    embc[(size_t)b * 512 + e]        = f2b(v0);
    embc[(size_t)b * 512 + 256 + e]  = f2b(v1);
}

__global__ void finalize_emb(const float* __restrict__ emb1f,
                             const float* __restrict__ sfLast,
                             const unsigned short* __restrict__ h_i,
                             const float* __restrict__ emb_row,
                             unsigned short* __restrict__ embc,
                             float* __restrict__ embcF)
{
    int b = blockIdx.x, e = threadIdx.x;
    float v = emb1f[b * Ev + e] + sfLast[b] * b2f(h_i[b * Ev + e]);
    float w = emb_row[e];
    embcF[(size_t)b * 512 + e]       = v;
    embcF[(size_t)b * 512 + 256 + e] = w;
    embc[(size_t)b * 512 + e]        = f2b(v);
    embc[(size_t)b * 512 + 256 + e]  = f2b(w);
}

__global__ void write_out(const float* __restrict__ prob,
                          const float* __restrict__ embcF,
                          float* __restrict__ out)
{
    int b = blockIdx.x, tid = threadIdx.x;
    for (int r = tid; r < NP1; r += 256)
        out[(size_t)b * NP1 + r] = prob[(size_t)b * PSTR + r];
    for (int j = tid; j < 512; j += 256)
        out[(size_t)Bv * NP1 + (size_t)b * 512 + j] = embcF[(size_t)b * 512 + j];
}

extern "C" void kernel_launch(void* const* d_in, const int* in_sizes, int n_in,
                              void* d_out, int out_size, void* d_ws, size_t ws_size,
                              hipStream_t stream)
{
    const int*   bodys = (const int*)d_in[0];
    const float* emb_w = (const float*)d_in[1];
    const float* w_ih  = (const float*)d_in[2];
    const float* w_hh  = (const float*)d_in[3];
    const float* b_ih  = (const float*)d_in[4];
    const float* b_hh  = (const float*)d_in[5];
    const float* fc1_w = (const float*)d_in[6];
    const float* fc1_b = (const float*)d_in[7];
    const float* fc2_w = (const float*)d_in[8];
    const float* fc2_b = (const float*)d_in[9];
    float* out = (float*)d_out;

    char* ws = (char*)d_ws;
    size_t off = 0;
    auto alloc = [&](size_t bytes) -> void* {
        void* p = ws + off;
        off += (bytes + 255) & ~(size_t)255;
        return p;
    };
    unsigned short* x       = (unsigned short*)alloc((size_t)Bv * Lv * Ev * 2);
    unsigned short* hs      = (unsigned short*)alloc((size_t)Lv * Bv * Ev * 2);
    float*          cbuf    = (float*)alloc((size_t)Bv * Ev * 4);
    float*          g       = (float*)alloc((size_t)Bv * 1024 * 4);
    unsigned short* embT    = (unsigned short*)alloc((size_t)Ev * PSTR * 2);
    unsigned short* sfA     = (unsigned short*)alloc((size_t)Bv * PSTR * 2);
    float*          sfLast  = (float*)alloc((size_t)Bv * 4);
    float*          prob    = (float*)alloc((size_t)Bv * PSTR * 4);
    float*          emb1f   = (float*)alloc((size_t)Bv * Ev * 4);
    unsigned short* embc    = (unsigned short*)alloc((size_t)Bv * 512 * 2);
    float*          embcF   = (float*)alloc((size_t)Bv * 512 * 4);
    unsigned short* hiddenA = (unsigned short*)alloc((size_t)Bv * Ev * 2);
    unsigned short* w_ih_b  = (unsigned short*)alloc((size_t)1024 * Ev * 2);
    unsigned short* w_hh_b  = (unsigned short*)alloc((size_t)1024 * Ev * 2);
    unsigned short* fc1_w_b = (unsigned short*)alloc((size_t)Ev * 512 * 2);
    unsigned short* fc2_w_b = (unsigned short*)alloc((size_t)NP1 * Ev * 2);
    (void)ws_size; (void)in_sizes; (void)n_in; (void)out_size;

    // f32 -> bf16 weight conversions (once per launch)
    conv_f2b<<<256, 256, 0, stream>>>(w_ih,  w_ih_b,  1024 * Ev);
    conv_f2b<<<256, 256, 0, stream>>>(w_hh,  w_hh_b,  1024 * Ev);
    conv_f2b<<<128, 256, 0, stream>>>(fc1_w, fc1_w_b, Ev * 512);
    conv_f2b<<<1024, 256, 0, stream>>>(fc2_w, fc2_w_b, NP1 * Ev);
    embed_k<<<Bv * Lv, 256, 0, stream>>>(bodys, emb_w, x);
    transpose_emb<<<dim3(40, 256), 256, 0, stream>>>(emb_w, embT);

    // LSTM: 8 steps
    for (int t = 0; t < Lv; ++t) {
        gemm_bt<<<dim3(16, 16, 1), 256, 0, stream>>>(
            x + t * Ev, Lv * Ev, w_ih_b, Ev,
            (t == 0) ? nullptr : (hs + (size_t)(t - 1) * Bv * Ev), Ev, w_hh_b, Ev,
            b_ih, b_hh,
            Ev, Ev, 1024, 0,
            g, nullptr, 1024);
        lstm_gates<<<Bv, 256, 0, stream>>>(g, cbuf, hs + (size_t)t * Bv * Ev, t);
    }

    for (int i = 0; i < 7; ++i) {
        if (i == 0) {
            concat0<<<Bv, 256, 0, stream>>>(bodys, emb_w, embc, embcF);
        } else {
            hipMemsetAsync(emb1f, 0, (size_t)Bv * Ev * 4, stream);
            // emb_1 partial: sfA(1024 x 10016) @ embT^T(10016 x 256), split-K=4
            gemm_bt<<<dim3(16, 4, 4), 256, 0, stream>>>(
                sfA, PSTR, embT, PSTR, nullptr, 0, nullptr, 0,
                nullptr, nullptr,
                PSTR, 2528, Ev, 2,
                emb1f, nullptr, Ev);
            finalize_emb<<<Bv, 256, 0, stream>>>(
                emb1f, sfLast, hs + (size_t)i * Bv * Ev,
                emb_w + (size_t)(i + 1) * Ev, embc, embcF);
        }
        // fc1: hidden = relu(embc(1024x512) @ fc1_w^T) -> bf16
        gemm_bt<<<dim3(16, 4, 1), 256, 0, stream>>>(
            embc, 512, fc1_w_b, 512, nullptr, 0, nullptr, 0,
            fc1_b, nullptr,
            512, 512, Ev, 1,
            nullptr, hiddenA, Ev);
        // fc2: prob = hidden(1024x256) @ fc2_w^T -> f32 (ldc PSTR)
        gemm_bt<<<dim3(16, 157, 1), 256, 0, stream>>>(
            hiddenA, Ev, fc2_w_b, Ev, nullptr, 0, nullptr, 0,
            fc2_b, nullptr,
            Ev, Ev, NP1, 0,
            prob, nullptr, PSTR);
        if (i < 6) softmax_k<<<Bv, 256, 0, stream>>>(prob, sfA, sfLast);
    }

    write_out<<<Bv, 256, 0, stream>>>(prob, embcF, out);
}

// Round 3
// 1012.445 us; speedup vs baseline: 1.6868x; 1.6868x over previous
//
#include <hip/hip_runtime.h>

#define Bv 1024
#define Ev 256
#define Lv 8
#define Rv 10000
#define NP1 10001
#define PSTR 10016      // padded K stride for softmax@emb_w (multiple of 32)
#define NPAD 10112      // fc2 rows padded to 79*128
#define BM 128
#define BN 128
#define BK 32

typedef __attribute__((ext_vector_type(8))) short bf16x8;
typedef __attribute__((ext_vector_type(4))) float f32x4;

__device__ __forceinline__ float b2f(unsigned short u) {
    union { unsigned int i; float f; } v; v.i = ((unsigned int)u) << 16; return v.f;
}
__device__ __forceinline__ unsigned short f2b(float f) {
    union { float f; unsigned int i; } v; v.f = f;
    unsigned int r = v.i + 0x7fffu + ((v.i >> 16) & 1u);
    return (unsigned short)(r >> 16);
}
__device__ __forceinline__ void glds16(const void* g, void* l) {
    __builtin_amdgcn_global_load_lds(
        (const __attribute__((address_space(1))) void*)g,
        (__attribute__((address_space(3))) void*)l, 16, 0, 0);
}

// Tiled MFMA GEMM: C = A1·W1^T (+ A2·W2^T) + bias1 (+bias2).
// A: (M x K) bf16 row-major; W: (N x K) bf16 row-major. 128x128 tile, BK=32.
// LDS chunk-swizzle: chunk c holds global col8 = (c&3)^(row&3)^((row>>2)&3).
// mode 0: f32 store   mode 1: bf16 relu store   mode 2: f32 atomicAdd (split-K)
__global__ __launch_bounds__(256) void gemm_tile(
    const unsigned short* __restrict__ A1, int lda1,
    const unsigned short* __restrict__ W1, int ldw1,
    const unsigned short* __restrict__ A2, int lda2,
    const unsigned short* __restrict__ W2, int ldw2,
    const float* __restrict__ bias1,
    const float* __restrict__ bias2,
    int Ktot, int kchunk, int Ncols, int mode,
    float* __restrict__ outF, unsigned short* __restrict__ outB, int ldc)
{
    __shared__ unsigned short As[BM * BK];   // 8 KB
    __shared__ unsigned short Bs[BN * BK];   // 8 KB

    int tid  = threadIdx.x;
    int wave = tid >> 6;
    int lane = tid & 63;
    int quad = lane >> 4;
    int l16  = lane & 15;
    int wm = (wave & 1) * 64;
    int wn = (wave >> 1) * 64;
    int m0 = blockIdx.x * BM;
    int n0 = blockIdx.y * BN;
    int k0 = blockIdx.z * kchunk;
    int k1 = k0 + kchunk; if (k1 > Ktot) k1 = Ktot;

    f32x4 acc[4][4];
#pragma unroll
    for (int i = 0; i < 4; ++i)
#pragma unroll
        for (int j = 0; j < 4; ++j) acc[i][j] = (f32x4){0.f, 0.f, 0.f, 0.f};

    // staging chunk ids (2 calls each for A and B per thread)
    int c0 = tid, c1 = 256 + tid;
    int row0 = c0 >> 2, row1 = c1 >> 2;
    int g80 = ((c0 & 3) ^ (row0 & 3) ^ ((row0 >> 2) & 3)) * 8;
    int g81 = ((c1 & 3) ^ (row1 & 3) ^ ((row1 >> 2) & 3)) * 8;
    unsigned short* ldsA0 = As + (size_t)(wave * 64) * 8;
    unsigned short* ldsA1 = As + (size_t)(256 + wave * 64) * 8;
    unsigned short* ldsB0 = Bs + (size_t)(wave * 64) * 8;
    unsigned short* ldsB1 = Bs + (size_t)(256 + wave * 64) * 8;

    int nSrc = A2 ? 2 : 1;
    bool first = true;
    for (int s = 0; s < nSrc; ++s) {
        const unsigned short* A = s ? A2 : A1; int lda = s ? lda2 : lda1;
        const unsigned short* W = s ? W2 : W1; int ldw = s ? ldw2 : ldw1;
        for (int k = k0; k < k1; k += BK) {
            if (!first) __syncthreads();   // protect LDS still being read
            first = false;
            glds16(A + (size_t)(m0 + row0) * lda + k + g80, ldsA0);
            glds16(A + (size_t)(m0 + row1) * lda + k + g81, ldsA1);
            glds16(W + (size_t)(n0 + row0) * ldw + k + g80, ldsB0);
            glds16(W + (size_t)(n0 + row1) * ldw + k + g81, ldsB1);
            asm volatile("s_waitcnt vmcnt(0)" ::: "memory");
            __syncthreads();

            bf16x8 af[4], bfr[4];
#pragma unroll
            for (int t = 0; t < 4; ++t) {
                int m = wm + t * 16 + l16;
                int ca = quad ^ (m & 3) ^ ((m >> 2) & 3);
                af[t] = *(const bf16x8*)(As + m * 32 + ca * 8);
                int n = wn + t * 16 + l16;
                int cb = quad ^ (n & 3) ^ ((n >> 2) & 3);
                bfr[t] = *(const bf16x8*)(Bs + n * 32 + cb * 8);
            }
#pragma unroll
            for (int i = 0; i < 4; ++i)
#pragma unroll
                for (int j = 0; j < 4; ++j)
                    acc[i][j] = __builtin_amdgcn_mfma_f32_16x16x32_bf16(
                        af[i], bfr[j], acc[i][j], 0, 0, 0);
        }
    }

    // D mapping: col = lane&15, row = quad*4 + reg
#pragma unroll
    for (int j = 0; j < 4; ++j) {
        int n = n0 + wn + j * 16 + l16;
        if (n >= Ncols) continue;
        float bsum = 0.f;
        if (bias1) bsum += bias1[n];
        if (bias2) bsum += bias2[n];
#pragma unroll
        for (int i = 0; i < 4; ++i) {
            int mBase = m0 + wm + i * 16 + quad * 4;
#pragma unroll
            for (int r = 0; r < 4; ++r) {
                float v = acc[i][j][r] + bsum;
                size_t idx = (size_t)(mBase + r) * ldc + n;
                if (mode == 0)      outF[idx] = v;
                else if (mode == 1) outB[idx] = f2b(v > 0.f ? v : 0.f);
                else                atomicAdd(&outF[idx], v);
            }
        }
    }
}

__global__ void conv_f2b(const float* __restrict__ src,
                         unsigned short* __restrict__ dst, int n)
{
    for (int i = blockIdx.x * 256 + threadIdx.x; i < n; i += gridDim.x * 256)
        dst[i] = f2b(src[i]);
}

__global__ void embed_k(const int* __restrict__ bodys,
                        const float* __restrict__ emb_w,
                        unsigned short* __restrict__ x)
{
    int blk = blockIdx.x;  // b*L + l
    x[(size_t)blk * Ev + threadIdx.x] =
        f2b(emb_w[(size_t)bodys[blk] * Ev + threadIdx.x]);
}

// coalesced 32x32 tiled transpose: embT[e][k] = bf16(emb_w[k][e]), k-pad zeroed
__global__ void transpose_emb(const float* __restrict__ emb_w,
                              unsigned short* __restrict__ embT)
{
    __shared__ float tile[32][33];
    int kt = blockIdx.x * 32, et = blockIdx.y * 32;
    int tx = threadIdx.x & 31, ty = threadIdx.x >> 5;   // 32 x 8
#pragma unroll
    for (int r = ty; r < 32; r += 8) {
        int k = kt + r;
        tile[r][tx] = (k < Rv) ? emb_w[(size_t)k * Ev + et + tx] : 0.f;
    }
    __syncthreads();
#pragma unroll
    for (int r = ty; r < 32; r += 8) {
        embT[(size_t)(et + r) * PSTR + kt + tx] = f2b(tile[tx][r]);
    }
}

__global__ void lstm_gates(const float* __restrict__ g, float* __restrict__ c,
                           unsigned short* __restrict__ hout, int t)
{
    int b = blockIdx.x, e = threadIdx.x;
    const float* gr = g + (size_t)b * 1024;
    float gi = gr[e], gf = gr[256 + e], gc = gr[512 + e], go = gr[768 + e];
    float cp = (t == 0) ? 0.f : c[b * Ev + e];
    float si = 1.f / (1.f + expf(-gi));
    float sf = 1.f / (1.f + expf(-gf));
    float so = 1.f / (1.f + expf(-go));
    float cn = sf * cp + si * tanhf(gc);
    float hn = so * tanhf(cn);
    c[b * Ev + e] = cn;
    hout[b * Ev + e] = f2b(hn);
}

__global__ __launch_bounds__(256) void softmax_k(const float* __restrict__ prob,
                                                 unsigned short* __restrict__ sfA,
                                                 float* __restrict__ sfLast)
{
    int b = blockIdx.x, tid = threadIdx.x;
    int wave = tid >> 6, lane = tid & 63;
    __shared__ float redm[4], reds[4];
    const float* pr = prob + (size_t)b * PSTR;
    float m = -1e30f;
    for (int k = tid; k < NP1; k += 256) m = fmaxf(m, pr[k]);
    for (int off = 32; off; off >>= 1) m = fmaxf(m, __shfl_down(m, off));
    if (lane == 0) redm[wave] = m;
    __syncthreads();
    m = fmaxf(fmaxf(redm[0], redm[1]), fmaxf(redm[2], redm[3]));
    float s = 0.f;
    for (int k = tid; k < NP1; k += 256) s += expf(pr[k] - m);
    for (int off = 32; off; off >>= 1) s += __shfl_down(s, off);
    if (lane == 0) reds[wave] = s;
    __syncthreads();
    s = reds[0] + reds[1] + reds[2] + reds[3];
    float inv = 1.f / s;
    for (int k = tid; k < PSTR; k += 256) {
        size_t idx = (size_t)b * PSTR + k;
        if (k < Rv) {
            sfA[idx] = f2b(expf(pr[k] - m) * inv);
        } else {
            sfA[idx] = 0;
            if (k == Rv) sfLast[b] = expf(pr[k] - m) * inv;
        }
    }
}

__global__ void concat0(const int* __restrict__ bodys,
                        const float* __restrict__ emb_w,
                        unsigned short* __restrict__ embc,
                        float* __restrict__ embcF)
{
    int b = blockIdx.x, e = threadIdx.x;
    float v0 = emb_w[(size_t)bodys[b * Lv + 0] * Ev + e];
    float v1 = emb_w[(size_t)bodys[b * Lv + 1] * Ev + e];
    embcF[(size_t)b * 512 + e]       = v0;
    embcF[(size_t)b * 512 + 256 + e] = v1;
    embc[(size_t)b * 512 + e]        = f2b(v0);
    embc[(size_t)b * 512 + 256 + e]  = f2b(v1);
}

__global__ void finalize_emb(const float* __restrict__ emb1f,
                             const float* __restrict__ sfLast,
                             const unsigned short* __restrict__ h_i,
                             const float* __restrict__ emb_row,
                             unsigned short* __restrict__ embc,
                             float* __restrict__ embcF)
{
    int b = blockIdx.x, e = threadIdx.x;
    float v = emb1f[b * Ev + e] + sfLast[b] * b2f(h_i[b * Ev + e]);
    float w = emb_row[e];
    embcF[(size_t)b * 512 + e]       = v;
    embcF[(size_t)b * 512 + 256 + e] = w;
    embc[(size_t)b * 512 + e]        = f2b(v);
    embc[(size_t)b * 512 + 256 + e]  = f2b(w);
}

__global__ void write_out(const float* __restrict__ prob,
                          const float* __restrict__ embcF,
                          float* __restrict__ out)
{
    int b = blockIdx.x, tid = threadIdx.x;
    for (int r = tid; r < NP1; r += 256)
        out[(size_t)b * NP1 + r] = prob[(size_t)b * PSTR + r];
    for (int j = tid; j < 512; j += 256)
        out[(size_t)Bv * NP1 + (size_t)b * 512 + j] = embcF[(size_t)b * 512 + j];
}

extern "C" void kernel_launch(void* const* d_in, const int* in_sizes, int n_in,
                              void* d_out, int out_size, void* d_ws, size_t ws_size,
                              hipStream_t stream)
{
    const int*   bodys = (const int*)d_in[0];
    const float* emb_w = (const float*)d_in[1];
    const float* w_ih  = (const float*)d_in[2];
    const float* w_hh  = (const float*)d_in[3];
    const float* b_ih  = (const float*)d_in[4];
    const float* b_hh  = (const float*)d_in[5];
    const float* fc1_w = (const float*)d_in[6];
    const float* fc1_b = (const float*)d_in[7];
    const float* fc2_w = (const float*)d_in[8];
    const float* fc2_b = (const float*)d_in[9];
    float* out = (float*)d_out;

    char* ws = (char*)d_ws;
    size_t off = 0;
    auto alloc = [&](size_t bytes) -> void* {
        void* p = ws + off;
        off += (bytes + 255) & ~(size_t)255;
        return p;
    };
    unsigned short* x       = (unsigned short*)alloc((size_t)Bv * Lv * Ev * 2);
    unsigned short* hs      = (unsigned short*)alloc((size_t)Lv * Bv * Ev * 2);
    float*          cbuf    = (float*)alloc((size_t)Bv * Ev * 4);
    float*          g       = (float*)alloc((size_t)Bv * 1024 * 4);
    unsigned short* embT    = (unsigned short*)alloc((size_t)Ev * PSTR * 2);
    unsigned short* sfA     = (unsigned short*)alloc((size_t)Bv * PSTR * 2);
    float*          sfLast  = (float*)alloc((size_t)Bv * 4);
    float*          prob    = (float*)alloc((size_t)Bv * PSTR * 4);
    float*          emb1f   = (float*)alloc((size_t)Bv * Ev * 4);
    unsigned short* embc    = (unsigned short*)alloc((size_t)Bv * 512 * 2);
    float*          embcF   = (float*)alloc((size_t)Bv * 512 * 4);
    unsigned short* hiddenA = (unsigned short*)alloc((size_t)Bv * Ev * 2);
    unsigned short* w_ih_b  = (unsigned short*)alloc((size_t)1024 * Ev * 2);
    unsigned short* w_hh_b  = (unsigned short*)alloc((size_t)1024 * Ev * 2);
    unsigned short* fc1_w_b = (unsigned short*)alloc((size_t)Ev * 512 * 2);
    unsigned short* fc2_w_b = (unsigned short*)alloc((size_t)NPAD * Ev * 2);
    (void)ws_size; (void)in_sizes; (void)n_in; (void)out_size;

    // weight conversions (once per launch)
    hipMemsetAsync(fc2_w_b, 0, (size_t)NPAD * Ev * 2, stream);  // zero the row pad
    conv_f2b<<<256, 256, 0, stream>>>(w_ih,  w_ih_b,  1024 * Ev);
    conv_f2b<<<256, 256, 0, stream>>>(w_hh,  w_hh_b,  1024 * Ev);
    conv_f2b<<<128, 256, 0, stream>>>(fc1_w, fc1_w_b, Ev * 512);
    conv_f2b<<<1024, 256, 0, stream>>>(fc2_w, fc2_w_b, NP1 * Ev);
    embed_k<<<Bv * Lv, 256, 0, stream>>>(bodys, emb_w, x);
    transpose_emb<<<dim3(PSTR / 32, Ev / 32), 256, 0, stream>>>(emb_w, embT);

    // LSTM: 8 steps, dual-source tiled GEMM (x_t·w_ih^T + h·w_hh^T)
    for (int t = 0; t < Lv; ++t) {
        gemm_tile<<<dim3(8, 8, 1), 256, 0, stream>>>(
            x + t * Ev, Lv * Ev, w_ih_b, Ev,
            (t == 0) ? nullptr : (hs + (size_t)(t - 1) * Bv * Ev), Ev, w_hh_b, Ev,
            b_ih, b_hh,
            Ev, Ev, 1024, 0,
            g, nullptr, 1024);
        lstm_gates<<<Bv, 256, 0, stream>>>(g, cbuf, hs + (size_t)t * Bv * Ev, t);
    }

    for (int i = 0; i < 7; ++i) {
        if (i == 0) {
            concat0<<<Bv, 256, 0, stream>>>(bodys, emb_w, embc, embcF);
        } else {
            hipMemsetAsync(emb1f, 0, (size_t)Bv * Ev * 4, stream);
            // emb_1: sfA(1024 x 10016) @ embT^T -> (1024 x 256), split-K=16
            gemm_tile<<<dim3(8, 2, 16), 256, 0, stream>>>(
                sfA, PSTR, embT, PSTR, nullptr, 0, nullptr, 0,
                nullptr, nullptr,
                PSTR, 640, Ev, 2,
                emb1f, nullptr, Ev);
            finalize_emb<<<Bv, 256, 0, stream>>>(
                emb1f, sfLast, hs + (size_t)i * Bv * Ev,
                emb_w + (size_t)(i + 1) * Ev, embc, embcF);
        }
        // fc1: hidden = relu(embc(1024x512) @ fc1_w^T) -> bf16
        gemm_tile<<<dim3(8, 2, 1), 256, 0, stream>>>(
            embc, 512, fc1_w_b, 512, nullptr, 0, nullptr, 0,
            fc1_b, nullptr,
            512, 512, Ev, 1,
            nullptr, hiddenA, Ev);
        // fc2: prob = hidden(1024x256) @ fc2_w^T -> f32 (ldc PSTR)
        gemm_tile<<<dim3(8, NPAD / BN, 1), 256, 0, stream>>>(
            hiddenA, Ev, fc2_w_b, Ev, nullptr, 0, nullptr, 0,
            fc2_b, nullptr,
            Ev, Ev, NP1, 0,
            prob, nullptr, PSTR);
        if (i < 6) softmax_k<<<Bv, 256, 0, stream>>>(prob, sfA, sfLast);
    }

    write_out<<<Bv, 256, 0, stream>>>(prob, embcF, out);
}

// Round 4
// 841.793 us; speedup vs baseline: 2.0287x; 1.2027x over previous
//
#include <hip/hip_runtime.h>

#define Bv 1024
#define Ev 256
#define Lv 8
#define Rv 10000
#define NP1 10001
#define PS2 10240      // padded row stride (multiple of 2048 for softmax chunking)
#define NPAD 10112     // fc2 rows padded to 79*128
#define BM 128
#define BN 128
#define BK 32

typedef __attribute__((ext_vector_type(8))) short bf16x8;
typedef __attribute__((ext_vector_type(4))) float f32x4;

__device__ __forceinline__ float b2f(unsigned short u) {
    union { unsigned int i; float f; } v; v.i = ((unsigned int)u) << 16; return v.f;
}
__device__ __forceinline__ unsigned short f2b(float f) {
    union { float f; unsigned int i; } v; v.f = f;
    unsigned int r = v.i + 0x7fffu + ((v.i >> 16) & 1u);
    return (unsigned short)(r >> 16);
}
__device__ __forceinline__ void glds16(const void* g, void* l) {
    __builtin_amdgcn_global_load_lds(
        (const __attribute__((address_space(1))) void*)g,
        (__attribute__((address_space(3))) void*)l, 16, 0, 0);
}

// Tiled MFMA GEMM: C = A1·W1^T (+ A2·W2^T) + bias1 (+bias2).
// A: (M x K) bf16 row-major; W: (N x K) bf16 row-major. 128x128 tile, BK=32.
// mode 0: f32 store  1: bf16 relu  2: f32 atomicAdd (split-K)  3: bf16 plain
__global__ __launch_bounds__(256) void gemm_tile(
    const unsigned short* __restrict__ A1, int lda1,
    const unsigned short* __restrict__ W1, int ldw1,
    const unsigned short* __restrict__ A2, int lda2,
    const unsigned short* __restrict__ W2, int ldw2,
    const float* __restrict__ bias1,
    const float* __restrict__ bias2,
    int Ktot, int kchunk, int Ncols, int mode,
    float* __restrict__ outF, unsigned short* __restrict__ outB, int ldc)
{
    __shared__ unsigned short As[BM * BK];   // 8 KB
    __shared__ unsigned short Bs[BN * BK];   // 8 KB

    int tid  = threadIdx.x;
    int wave = tid >> 6;
    int lane = tid & 63;
    int quad = lane >> 4;
    int l16  = lane & 15;
    int wm = (wave & 1) * 64;
    int wn = (wave >> 1) * 64;
    int m0 = blockIdx.x * BM;
    int n0 = blockIdx.y * BN;
    int k0 = blockIdx.z * kchunk;
    int k1 = k0 + kchunk; if (k1 > Ktot) k1 = Ktot;

    f32x4 acc[4][4];
#pragma unroll
    for (int i = 0; i < 4; ++i)
#pragma unroll
        for (int j = 0; j < 4; ++j) acc[i][j] = (f32x4){0.f, 0.f, 0.f, 0.f};

    int c0 = tid, c1 = 256 + tid;
    int row0 = c0 >> 2, row1 = c1 >> 2;
    int g80 = ((c0 & 3) ^ (row0 & 3) ^ ((row0 >> 2) & 3)) * 8;
    int g81 = ((c1 & 3) ^ (row1 & 3) ^ ((row1 >> 2) & 3)) * 8;
    unsigned short* ldsA0 = As + (size_t)(wave * 64) * 8;
    unsigned short* ldsA1 = As + (size_t)(256 + wave * 64) * 8;
    unsigned short* ldsB0 = Bs + (size_t)(wave * 64) * 8;
    unsigned short* ldsB1 = Bs + (size_t)(256 + wave * 64) * 8;

    int nSrc = A2 ? 2 : 1;
    bool first = true;
    for (int s = 0; s < nSrc; ++s) {
        const unsigned short* A = s ? A2 : A1; int lda = s ? lda2 : lda1;
        const unsigned short* W = s ? W2 : W1; int ldw = s ? ldw2 : ldw1;
        for (int k = k0; k < k1; k += BK) {
            if (!first) __syncthreads();
            first = false;
            glds16(A + (size_t)(m0 + row0) * lda + k + g80, ldsA0);
            glds16(A + (size_t)(m0 + row1) * lda + k + g81, ldsA1);
            glds16(W + (size_t)(n0 + row0) * ldw + k + g80, ldsB0);
            glds16(W + (size_t)(n0 + row1) * ldw + k + g81, ldsB1);
            asm volatile("s_waitcnt vmcnt(0)" ::: "memory");
            __syncthreads();

            bf16x8 af[4], bfr[4];
#pragma unroll
            for (int t = 0; t < 4; ++t) {
                int m = wm + t * 16 + l16;
                int ca = quad ^ (m & 3) ^ ((m >> 2) & 3);
                af[t] = *(const bf16x8*)(As + m * 32 + ca * 8);
                int n = wn + t * 16 + l16;
                int cb = quad ^ (n & 3) ^ ((n >> 2) & 3);
                bfr[t] = *(const bf16x8*)(Bs + n * 32 + cb * 8);
            }
#pragma unroll
            for (int i = 0; i < 4; ++i)
#pragma unroll
                for (int j = 0; j < 4; ++j)
                    acc[i][j] = __builtin_amdgcn_mfma_f32_16x16x32_bf16(
                        af[i], bfr[j], acc[i][j], 0, 0, 0);
        }
    }

    // D mapping: col = lane&15, row = quad*4 + reg
#pragma unroll
    for (int j = 0; j < 4; ++j) {
        int n = n0 + wn + j * 16 + l16;
        if (n >= Ncols) continue;
        float bsum = 0.f;
        if (bias1) bsum += bias1[n];
        if (bias2) bsum += bias2[n];
#pragma unroll
        for (int i = 0; i < 4; ++i) {
            int mBase = m0 + wm + i * 16 + quad * 4;
#pragma unroll
            for (int r = 0; r < 4; ++r) {
                float v = acc[i][j][r] + bsum;
                size_t idx = (size_t)(mBase + r) * ldc + n;
                if (mode == 0)      outF[idx] = v;
                else if (mode == 1) outB[idx] = f2b(v > 0.f ? v : 0.f);
                else if (mode == 2) atomicAdd(&outF[idx], v);
                else                outB[idx] = f2b(v);
            }
        }
    }
}

__global__ void conv_f2b(const float* __restrict__ src,
                         unsigned short* __restrict__ dst, int n)
{
    for (int i = blockIdx.x * 256 + threadIdx.x; i < n; i += gridDim.x * 256)
        dst[i] = f2b(src[i]);
}

__global__ void embed_k(const int* __restrict__ bodys,
                        const float* __restrict__ emb_w,
                        unsigned short* __restrict__ x)
{
    int blk = blockIdx.x;  // b*L + l
    x[(size_t)blk * Ev + threadIdx.x] =
        f2b(emb_w[(size_t)bodys[blk] * Ev + threadIdx.x]);
}

// coalesced 32x32 tiled transpose: embT[e][k] = bf16(emb_w[k][e]), pad zeroed
__global__ void transpose_emb(const float* __restrict__ emb_w,
                              unsigned short* __restrict__ embT)
{
    __shared__ float tile[32][33];
    int kt = blockIdx.x * 32, et = blockIdx.y * 32;
    int tx = threadIdx.x & 31, ty = threadIdx.x >> 5;   // 32 x 8
#pragma unroll
    for (int r = ty; r < 32; r += 8) {
        int k = kt + r;
        tile[r][tx] = (k < Rv) ? emb_w[(size_t)k * Ev + et + tx] : 0.f;
    }
    __syncthreads();
#pragma unroll
    for (int r = ty; r < 32; r += 8) {
        embT[(size_t)(et + r) * PS2 + kt + tx] = f2b(tile[tx][r]);
    }
}

__global__ void lstm_gates(const float* __restrict__ g, float* __restrict__ c,
                           unsigned short* __restrict__ hout, int t)
{
    int b = blockIdx.x, e = threadIdx.x;
    const float* gr = g + (size_t)b * 1024;
    float gi = gr[e], gf = gr[256 + e], gc = gr[512 + e], go = gr[768 + e];
    float cp = (t == 0) ? 0.f : c[b * Ev + e];
    float si = 1.f / (1.f + expf(-gi));
    float sf = 1.f / (1.f + expf(-gf));
    float so = 1.f / (1.f + expf(-go));
    float cn = sf * cp + si * tanhf(gc);
    float hn = so * tanhf(cn);
    c[b * Ev + e] = cn;
    hout[b * Ev + e] = f2b(hn);
}

// single-pass register softmax over bf16 logits (stride PS2, valid < NP1).
// writes bf16 sf (cols < Rv; pad [Rv,PS2) zeroed) + f32 sfLast (col Rv).
__global__ __launch_bounds__(256) void softmax_k(
    const unsigned short* __restrict__ probB,
    unsigned short* __restrict__ sfA,
    float* __restrict__ sfLast)
{
    int b = blockIdx.x, tid = threadIdx.x;
    int wave = tid >> 6, lane = tid & 63;
    __shared__ float redm[4], reds[4];
    const unsigned short* pr = probB + (size_t)b * PS2;

    bf16x8 pv[5];
#pragma unroll
    for (int c = 0; c < 5; ++c)
        pv[c] = *(const bf16x8*)(pr + c * 2048 + tid * 8);

    float m = -1e30f;
#pragma unroll
    for (int c = 0; c < 5; ++c)
#pragma unroll
        for (int j = 0; j < 8; ++j) {
            int k = c * 2048 + tid * 8 + j;
            if (k < NP1) m = fmaxf(m, b2f((unsigned short)pv[c][j]));
        }
    for (int off = 32; off; off >>= 1) m = fmaxf(m, __shfl_down(m, off));
    if (lane == 0) redm[wave] = m;
    __syncthreads();
    m = fmaxf(fmaxf(redm[0], redm[1]), fmaxf(redm[2], redm[3]));

    float e[40];
    float s = 0.f;
#pragma unroll
    for (int c = 0; c < 5; ++c)
#pragma unroll
        for (int j = 0; j < 8; ++j) {
            int k = c * 2048 + tid * 8 + j;
            float v = (k < NP1) ? expf(b2f((unsigned short)pv[c][j]) - m) : 0.f;
            e[c * 8 + j] = v;
            s += v;
        }
    for (int off = 32; off; off >>= 1) s += __shfl_down(s, off);
    if (lane == 0) reds[wave] = s;
    __syncthreads();
    s = reds[0] + reds[1] + reds[2] + reds[3];
    float inv = 1.f / s;

    unsigned short* sr = sfA + (size_t)b * PS2;
#pragma unroll
    for (int c = 0; c < 5; ++c) {
        bf16x8 w;
#pragma unroll
        for (int j = 0; j < 8; ++j) {
            int k = c * 2048 + tid * 8 + j;
            float v = (k < Rv) ? e[c * 8 + j] * inv : 0.f;
            w[j] = (short)f2b(v);
            if (k == Rv) sfLast[b] = e[c * 8 + j] * inv;
        }
        *(bf16x8*)(sr + c * 2048 + tid * 8) = w;
    }
}

__global__ void concat0(const int* __restrict__ bodys,
                        const float* __restrict__ emb_w,
                        unsigned short* __restrict__ embc,
                        float* __restrict__ embcF)
{
    int b = blockIdx.x, e = threadIdx.x;
    float v0 = emb_w[(size_t)bodys[b * Lv + 0] * Ev + e];
    float v1 = emb_w[(size_t)bodys[b * Lv + 1] * Ev + e];
    embcF[(size_t)b * 512 + e]       = v0;
    embcF[(size_t)b * 512 + 256 + e] = v1;
    embc[(size_t)b * 512 + e]        = f2b(v0);
    embc[(size_t)b * 512 + 256 + e]  = f2b(v1);
}

__global__ void finalize_emb(const float* __restrict__ emb1f,
                             const float* __restrict__ sfLast,
                             const unsigned short* __restrict__ h_i,
                             const float* __restrict__ emb_row,
                             unsigned short* __restrict__ embc,
                             float* __restrict__ embcF)
{
    int b = blockIdx.x, e = threadIdx.x;
    float v = emb1f[b * Ev + e] + sfLast[b] * b2f(h_i[b * Ev + e]);
    float w = emb_row[e];
    embcF[(size_t)b * 512 + e]       = v;
    embcF[(size_t)b * 512 + 256 + e] = w;
    embc[(size_t)b * 512 + e]        = f2b(v);
    embc[(size_t)b * 512 + 256 + e]  = f2b(w);
}

__global__ void copy_embc(const float* __restrict__ embcF,
                          float* __restrict__ out)
{
    int b = blockIdx.x, tid = threadIdx.x;
    out[(size_t)Bv * NP1 + (size_t)b * 512 + tid]       = embcF[(size_t)b * 512 + tid];
    out[(size_t)Bv * NP1 + (size_t)b * 512 + 256 + tid] = embcF[(size_t)b * 512 + 256 + tid];
}

extern "C" void kernel_launch(void* const* d_in, const int* in_sizes, int n_in,
                              void* d_out, int out_size, void* d_ws, size_t ws_size,
                              hipStream_t stream)
{
    const int*   bodys = (const int*)d_in[0];
    const float* emb_w = (const float*)d_in[1];
    const float* w_ih  = (const float*)d_in[2];
    const float* w_hh  = (const float*)d_in[3];
    const float* b_ih  = (const float*)d_in[4];
    const float* b_hh  = (const float*)d_in[5];
    const float* fc1_w = (const float*)d_in[6];
    const float* fc1_b = (const float*)d_in[7];
    const float* fc2_w = (const float*)d_in[8];
    const float* fc2_b = (const float*)d_in[9];
    float* out = (float*)d_out;

    char* ws = (char*)d_ws;
    size_t off = 0;
    auto alloc = [&](size_t bytes) -> void* {
        void* p = ws + off;
        off += (bytes + 255) & ~(size_t)255;
        return p;
    };
    unsigned short* x       = (unsigned short*)alloc((size_t)Bv * Lv * Ev * 2);
    unsigned short* hs      = (unsigned short*)alloc((size_t)Lv * Bv * Ev * 2);
    float*          cbuf    = (float*)alloc((size_t)Bv * Ev * 4);
    float*          g       = (float*)alloc((size_t)Bv * 1024 * 4);
    unsigned short* embT    = (unsigned short*)alloc((size_t)Ev * PS2 * 2);
    unsigned short* sfA     = (unsigned short*)alloc((size_t)Bv * PS2 * 2);
    float*          sfLast  = (float*)alloc((size_t)Bv * 4);
    unsigned short* probB   = (unsigned short*)alloc((size_t)Bv * PS2 * 2);
    float*          emb1f   = (float*)alloc((size_t)Bv * Ev * 4);
    unsigned short* embc    = (unsigned short*)alloc((size_t)Bv * 512 * 2);
    float*          embcF   = (float*)alloc((size_t)Bv * 512 * 4);
    unsigned short* hiddenA = (unsigned short*)alloc((size_t)Bv * Ev * 2);
    unsigned short* w_ih_b  = (unsigned short*)alloc((size_t)1024 * Ev * 2);
    unsigned short* w_hh_b  = (unsigned short*)alloc((size_t)1024 * Ev * 2);
    unsigned short* fc1_w_b = (unsigned short*)alloc((size_t)Ev * 512 * 2);
    unsigned short* fc2_w_b = (unsigned short*)alloc((size_t)NPAD * Ev * 2);
    (void)ws_size; (void)in_sizes; (void)n_in; (void)out_size;

    hipMemsetAsync(fc2_w_b, 0, (size_t)NPAD * Ev * 2, stream);
    conv_f2b<<<256, 256, 0, stream>>>(w_ih,  w_ih_b,  1024 * Ev);
    conv_f2b<<<256, 256, 0, stream>>>(w_hh,  w_hh_b,  1024 * Ev);
    conv_f2b<<<128, 256, 0, stream>>>(fc1_w, fc1_w_b, Ev * 512);
    conv_f2b<<<1024, 256, 0, stream>>>(fc2_w, fc2_w_b, NP1 * Ev);
    embed_k<<<Bv * Lv, 256, 0, stream>>>(bodys, emb_w, x);
    transpose_emb<<<dim3(PS2 / 32, Ev / 32), 256, 0, stream>>>(emb_w, embT);

    // LSTM: 8 steps, dual-source tiled GEMM (x_t·w_ih^T + h·w_hh^T)
    for (int t = 0; t < Lv; ++t) {
        gemm_tile<<<dim3(8, 8, 1), 256, 0, stream>>>(
            x + t * Ev, Lv * Ev, w_ih_b, Ev,
            (t == 0) ? nullptr : (hs + (size_t)(t - 1) * Bv * Ev), Ev, w_hh_b, Ev,
            b_ih, b_hh,
            Ev, Ev, 1024, 0,
            g, nullptr, 1024);
        lstm_gates<<<Bv, 256, 0, stream>>>(g, cbuf, hs + (size_t)t * Bv * Ev, t);
    }

    for (int i = 0; i < 7; ++i) {
        if (i == 0) {
            concat0<<<Bv, 256, 0, stream>>>(bodys, emb_w, embc, embcF);
        } else {
            hipMemsetAsync(emb1f, 0, (size_t)Bv * Ev * 4, stream);
            // emb_1: sfA(1024 x PS2) @ embT^T -> (1024 x 256), split-K=16
            gemm_tile<<<dim3(8, 2, 16), 256, 0, stream>>>(
                sfA, PS2, embT, PS2, nullptr, 0, nullptr, 0,
                nullptr, nullptr,
                PS2, 640, Ev, 2,
                emb1f, nullptr, Ev);
            finalize_emb<<<Bv, 256, 0, stream>>>(
                emb1f, sfLast, hs + (size_t)i * Bv * Ev,
                emb_w + (size_t)(i + 1) * Ev, embc, embcF);
        }
        // fc1: hidden = relu(embc(1024x512) @ fc1_w^T) -> bf16
        gemm_tile<<<dim3(8, 2, 1), 256, 0, stream>>>(
            embc, 512, fc1_w_b, 512, nullptr, 0, nullptr, 0,
            fc1_b, nullptr,
            512, 512, Ev, 1,
            nullptr, hiddenA, Ev);
        // fc2: prob = hidden(1024x256) @ fc2_w^T
        if (i < 6) {
            // bf16 logits for softmax, stride PS2
            gemm_tile<<<dim3(8, NPAD / BN, 1), 256, 0, stream>>>(
                hiddenA, Ev, fc2_w_b, Ev, nullptr, 0, nullptr, 0,
                fc2_b, nullptr,
                Ev, Ev, NP1, 3,
                nullptr, probB, PS2);
            softmax_k<<<Bv, 256, 0, stream>>>(probB, sfA, sfLast);
        } else {
            // final iteration: f32 straight into d_out (rows of NP1)
            gemm_tile<<<dim3(8, NPAD / BN, 1), 256, 0, stream>>>(
                hiddenA, Ev, fc2_w_b, Ev, nullptr, 0, nullptr, 0,
                fc2_b, nullptr,
                Ev, Ev, NP1, 0,
                out, nullptr, NP1);
        }
    }

    copy_embc<<<Bv, 256, 0, stream>>>(embcF, out);
}